// Round 10
// baseline (307.592 us; speedup 1.0000x reference)
//
#include <hip/hip_runtime.h>
#include <hip/hip_bf16.h>
#include <math.h>

#define D 128
#define NUM_GRAPHS 64
#define CHUNK 8192          // edges per binning block
#define BUCK_SH 8           // bucket = col >> 8  (256 nodes per bucket)
#define BUCK_N 256
#define BCAP 8192           // fixed slot capacity per bucket (mean 4096, +64 sigma)
#define HROW 136            // LDS row stride (17x16B) for h1 tile

typedef __bf16 bf16x8 __attribute__((ext_vector_type(8)));
typedef __bf16 bf16x2 __attribute__((ext_vector_type(2)));
typedef float f32x4 __attribute__((ext_vector_type(4)));
typedef float f32x2 __attribute__((ext_vector_type(2)));

// fp8 e4m3 (OCP) helpers — HW converts on gfx950
__device__ inline unsigned char f32_to_fp8(float x) {
    int pk = __builtin_amdgcn_cvt_pk_fp8_f32(x, x, 0, false);
    return (unsigned char)(pk & 0xff);
}
// word-select operand must be a compile-time constant (round-6 lesson)
template <bool HI>
__device__ inline f32x2 fp8x2_to_f32(unsigned int us) {
    return __builtin_amdgcn_cvt_pk_f32_fp8(us, HI);
}
__device__ inline f32x2 fp8x2_to_f32_us(unsigned short us) {
    return __builtin_amdgcn_cvt_pk_f32_fp8((unsigned int)us, false);
}

// W fragment index: idx(k,f) for the 16x16x32 MFMA B-operand layout
__device__ inline int wfrag_idx(int k, int f) {
    int kc = k >> 5, quad = (k >> 3) & 3, j = k & 7;
    int ft = f >> 4, m = f & 15;
    int lane = quad * 16 + m;
    return (((ft << 2) | kc) * 64 + lane) * 8 + j;
}

// ---------------- FUSED: CSR bin pass (blocks [0,nchunk)) + layer-1 GEMM (rest) ----------------
// gemm blocks self-pack W1 -> LDS fragments (no prep dispatch, no global Wf1);
// bin needs only memset(gcur). Both halves fully independent -> one launch.
__launch_bounds__(256)
__global__ void k_bin_gemm(const int* __restrict__ ei, int* __restrict__ gcur,
                           int* __restrict__ bbuf, int nbuck, int E, int nchunk,
                           const float* __restrict__ X, const float* __restrict__ W1,
                           unsigned char* __restrict__ Y8, int N) {
    __shared__ int h[512];
    __shared__ int base[512];
    __shared__ __bf16 Wlds[16384];
    int tid = threadIdx.x;

    if (blockIdx.x >= nchunk) {
        // ---- pack W1 (f32, row-major k*D+f) into LDS fragments: coalesced float4 ----
        const float4* w4 = (const float4*)W1;
        for (int i = tid; i < 4096; i += 256) {
            float4 v = w4[i];
            int bkf = i * 4;
            int k = bkf >> 7, f0 = bkf & 127;
            Wlds[wfrag_idx(k, f0 + 0)] = (__bf16)v.x;
            Wlds[wfrag_idx(k, f0 + 1)] = (__bf16)v.y;
            Wlds[wfrag_idx(k, f0 + 2)] = (__bf16)v.z;
            Wlds[wfrag_idx(k, f0 + 3)] = (__bf16)v.w;
        }
        __syncthreads();

        // ---- MFMA gemm: Y8 = fp8(X @ W1), unscaled ----
        int bid = blockIdx.x - nchunk;
        int w = tid >> 6, lane = tid & 63;
        int quad = lane >> 4, m = lane & 15;
        int nodeA = bid * 64 + w * 16 + m;
        if (nodeA >= N) nodeA = N - 1;

        bf16x8 a[4];
#pragma unroll
        for (int kc = 0; kc < 4; kc++) {
            int kb = kc * 32 + quad * 8;
            f32x4 x0 = *(const f32x4*)(X + (size_t)nodeA * D + kb);
            f32x4 x1 = *(const f32x4*)(X + (size_t)nodeA * D + kb + 4);
#pragma unroll
            for (int j = 0; j < 4; j++) { a[kc][j] = (__bf16)x0[j]; a[kc][4 + j] = (__bf16)x1[j]; }
        }

        f32x4 d[8];
#pragma unroll
        for (int ft = 0; ft < 8; ft++) {
            d[ft] = (f32x4){0.f, 0.f, 0.f, 0.f};
#pragma unroll
            for (int kc = 0; kc < 4; kc++) {
                bf16x8 b = *(const bf16x8*)(Wlds + (((ft << 2) | kc) * 64 + lane) * 8);
                d[ft] = __builtin_amdgcn_mfma_f32_16x16x32_bf16(a[kc], b, d[ft], 0, 0, 0);
            }
        }

#pragma unroll
        for (int r = 0; r < 4; r++) {
            int node = bid * 64 + w * 16 + quad * 4 + r;
            if (node < N) {
#pragma unroll
                for (int ft = 0; ft < 8; ft++)
                    Y8[(size_t)node * D + ft * 16 + m] = f32_to_fp8(d[ft][r]);
            }
        }
        return;
    }

    // ---- bin pass ----
    for (int b = tid; b < nbuck; b += 256) h[b] = 0;
    __syncthreads();
    int lo = blockIdx.x * CHUNK;
    if (lo + CHUNK <= E) {
        const int4* c4 = (const int4*)(ei + E + lo);
#pragma unroll 2
        for (int i = tid; i < CHUNK / 4; i += 256) {
            int4 c = c4[i];
            atomicAdd(&h[c.x >> BUCK_SH], 1);
            atomicAdd(&h[c.y >> BUCK_SH], 1);
            atomicAdd(&h[c.z >> BUCK_SH], 1);
            atomicAdd(&h[c.w >> BUCK_SH], 1);
        }
    } else {
        for (int i = tid; i < CHUNK; i += 256) {
            int e = lo + i;
            if (e < E) atomicAdd(&h[ei[E + e] >> BUCK_SH], 1);
        }
    }
    __syncthreads();
    for (int b = tid; b < nbuck; b += 256) {
        base[b] = atomicAdd(&gcur[b], h[b]);
        h[b] = 0;
    }
    __syncthreads();
    if (lo + CHUNK <= E) {
        const int4* r4 = (const int4*)(ei + lo);
        const int4* c4 = (const int4*)(ei + E + lo);
#pragma unroll 2
        for (int i = tid; i < CHUNK / 4; i += 256) {
            int4 r = r4[i];
            int4 c = c4[i];
            int rr[4] = {r.x, r.y, r.z, r.w};
            int cc[4] = {c.x, c.y, c.z, c.w};
#pragma unroll
            for (int u = 0; u < 4; u++) {
                int b = cc[u] >> BUCK_SH;
                int pos = base[b] + atomicAdd(&h[b], 1);
                if (pos < BCAP) bbuf[(size_t)b * BCAP + pos] = rr[u] | ((cc[u] & (BUCK_N - 1)) << 17);
            }
        }
    } else {
        for (int i = tid; i < CHUNK; i += 256) {
            int e = lo + i;
            if (e < E) {
                int r = ei[e], c = ei[E + e];
                int b = c >> BUCK_SH;
                int pos = base[b] + atomicAdd(&h[b], 1);
                if (pos < BCAP) bbuf[(size_t)b * BCAP + pos] = r | ((c & (BUCK_N - 1)) << 17);
            }
        }
    }
}

// ---------------- CSR pass 2 + in-place z1 scaling + Wf2 pack (spread over blocks) ----------------
__global__ void k_place(const int* __restrict__ bbuf, const int* __restrict__ gcur,
                        int* __restrict__ esrc,
                        int* __restrict__ cnt, int* __restrict__ offs,
                        float* __restrict__ dis, unsigned char* __restrict__ z1,
                        const float* __restrict__ W2, __bf16* __restrict__ Wf2, int N) {
    __shared__ int h[256];
    __shared__ int sc[256];
    __shared__ int cur[256];
    __shared__ float sdis[256];
    int b = blockIdx.x, tid = threadIdx.x;

    // Wf2 pack: 42 fragment elems per block (391 blocks cover 16384)
    for (int q = tid; q < 42; q += 256) {
        int idx = b * 42 + q;
        if (idx < 16384) {
            int j = idx & 7, lane = (idx >> 3) & 63, kc = (idx >> 9) & 3, ft = idx >> 11;
            int k = kc * 32 + (lane >> 4) * 8 + j;
            int f = ft * 16 + (lane & 15);
            Wf2[idx] = (__bf16)W2[k * D + f];
        }
    }

    int start = b * BCAP;
    int count = gcur[b]; if (count > BCAP) count = BCAP;
    int end = start + count;
    h[tid] = 0;
    __syncthreads();
    for (int i = start + tid; i < end; i += 256) atomicAdd(&h[(bbuf[i] >> 17) & 255], 1);
    __syncthreads();
    int local = h[tid];
    sc[tid] = local;
    __syncthreads();
    for (int off = 1; off < 256; off <<= 1) {
        int xv = (tid >= off) ? sc[tid - off] : 0;
        __syncthreads();
        sc[tid] += xv;
        __syncthreads();
    }
    int excl = sc[tid] - local;
    cur[tid] = start + excl;
    int c = b * 256 + tid;
    float dv = rsqrtf(1.0f + (float)local);
    sdis[tid] = dv;
    if (c < N) {
        cnt[c]  = local;
        offs[c] = start + excl;
        dis[c]  = dv;                        // deg includes self-loop
    }
    __syncthreads();
    for (int i = start + tid; i < end; i += 256) {
        int p = bbuf[i];
        int pos = atomicAdd(&cur[(p >> 17) & 255], 1);
        esrc[pos] = p & 0x1FFFF;
    }
    // in-place scale of this bucket's z1 rows (r8-proven: agg_gemm 85->61)
    int nrows = N - b * 256; if (nrows > 256) nrows = 256; if (nrows < 0) nrows = 0;
    unsigned int* zp = (unsigned int*)(z1 + (size_t)b * 256 * D);
    for (int i = tid; i < nrows * 32; i += 256) {      // 32 dwords per 128B row
        int row = i >> 5;
        float s = sdis[row];
        unsigned int v = zp[i];
        f32x2 lo = fp8x2_to_f32<false>(v);
        f32x2 hi = fp8x2_to_f32<true>(v);
        unsigned int u = (unsigned int)__builtin_amdgcn_cvt_pk_fp8_f32(lo[0] * s, lo[1] * s, 0, false);
        u = (unsigned int)__builtin_amdgcn_cvt_pk_fp8_f32(hi[0] * s, hi[1] * s, (int)u, true);
        zp[i] = u;
    }
}

// ---------------- FUSED layer-1 agg + GEMM2: z2 = fp8(dis .* (leaky(agg(z1)+b1) @ W2)) ----------------
__launch_bounds__(256)
__global__ void k_agg_gemm(const unsigned char* __restrict__ Hs8,      // z1 scaled fp8
                           const int* __restrict__ offs, const int* __restrict__ cnt,
                           const float* __restrict__ dis, const int* __restrict__ esrc,
                           const float* __restrict__ bias,             // b1
                           const __bf16* __restrict__ Wfrag,           // Wf2
                           unsigned char* __restrict__ Y8, int N) {    // z2 scaled fp8
    __shared__ __bf16 hl[32 * HROW];   // 32 nodes x 128 feats, padded rows (17x16B)
    int tid = threadIdx.x;
    int w = tid >> 6, lane = tid & 63;
    int node0 = blockIdx.x * 32 + w * 8;
    float b0 = bias[lane * 2], b1v = bias[lane * 2 + 1];

    for (int nn = 0; nn < 8; nn++) {
        int node = node0 + nn;
        if (node < N) {
            int start = offs[node];
            int len = cnt[node];
            float di = dis[node];
            f32x2 h = fp8x2_to_f32_us(*(const unsigned short*)(Hs8 + (size_t)node * D + lane * 2));
            float acc0 = h[0];               // self-loop term (already dis-scaled)
            float acc1 = h[1];

            for (int k0 = 0; k0 < len; k0 += 64) {
                int mm = len - k0; if (mm > 64) mm = 64;
                int ep = esrc[start + k0 + (lane < mm ? lane : 0)];
                int j = 0;
                for (; j + 16 <= mm; j += 16) {
                    int s[16]; unsigned short hv[16];
#pragma unroll
                    for (int u = 0; u < 16; u++) s[u] = __shfl(ep, j + u);
#pragma unroll
                    for (int u = 0; u < 16; u++) hv[u] = *(const unsigned short*)(Hs8 + (size_t)s[u] * D + lane * 2);
#pragma unroll
                    for (int u = 0; u < 16; u++) { f32x2 f = fp8x2_to_f32_us(hv[u]); acc0 += f[0]; acc1 += f[1]; }
                }
                for (; j + 4 <= mm; j += 4) {
                    int s[4]; unsigned short hv[4];
#pragma unroll
                    for (int u = 0; u < 4; u++) s[u] = __shfl(ep, j + u);
#pragma unroll
                    for (int u = 0; u < 4; u++) hv[u] = *(const unsigned short*)(Hs8 + (size_t)s[u] * D + lane * 2);
#pragma unroll
                    for (int u = 0; u < 4; u++) { f32x2 f = fp8x2_to_f32_us(hv[u]); acc0 += f[0]; acc1 += f[1]; }
                }
                for (; j < mm; j++) {
                    int s = __shfl(ep, j);
                    f32x2 f = fp8x2_to_f32_us(*(const unsigned short*)(Hs8 + (size_t)s * D + lane * 2));
                    acc0 += f[0]; acc1 += f[1];
                }
            }

            acc0 = acc0 * di + b0;
            acc1 = acc1 * di + b1v;
            acc0 = acc0 >= 0.f ? acc0 : 0.01f * acc0;
            acc1 = acc1 >= 0.f ? acc1 : 0.01f * acc1;
            bf16x2 o; o[0] = (__bf16)acc0; o[1] = (__bf16)acc1;
            *(bf16x2*)&hl[(w * 8 + nn) * HROW + lane * 2] = o;   // h1 -> LDS only
        } else {
            bf16x2 z; z[0] = (__bf16)0.f; z[1] = (__bf16)0.f;
            *(bf16x2*)&hl[(w * 8 + nn) * HROW + lane * 2] = z;
        }
    }
    __syncthreads();

    // ---- MFMA phase: wave w -> row tile (w&1)*16, ft half (w>>1)*4 ----
    int quad = lane >> 4, m = lane & 15;
    int rtile = w & 1, fthalf = w >> 1;
    int lrow = rtile * 16 + m;
    bf16x8 a[4];
#pragma unroll
    for (int kc = 0; kc < 4; kc++)
        a[kc] = *(const bf16x8*)&hl[lrow * HROW + kc * 32 + quad * 8];

    int nb = blockIdx.x * 32 + rtile * 16 + quad * 4;
    float scv[4];
#pragma unroll
    for (int r = 0; r < 4; r++) scv[r] = (nb + r < N) ? dis[nb + r] : 0.f;

#pragma unroll
    for (int ft = 0; ft < 4; ft++) {
        int gft = fthalf * 4 + ft;
        f32x4 dacc = (f32x4){0.f, 0.f, 0.f, 0.f};
#pragma unroll
        for (int kc = 0; kc < 4; kc++) {
            bf16x8 b = *(const bf16x8*)(Wfrag + (((gft << 2) | kc) * 64 + lane) * 8);
            dacc = __builtin_amdgcn_mfma_f32_16x16x32_bf16(a[kc], b, dacc, 0, 0, 0);
        }
#pragma unroll
        for (int r = 0; r < 4; r++) {
            int node = nb + r;
            if (node < N)
                Y8[(size_t)node * D + gft * 16 + m] = f32_to_fp8(dacc[r] * scv[r]);
        }
    }
}

// ---------------- layer-2 agg + bias + leaky + FUSED MEAN-POOL (block-level LDS reduce) ----------------
// h2 feeds ONLY the pool -> never materialized. Sorted batch => a block's 32
// nodes span <=2 graphs (general fallback for more). ~128 atomics/block, no fence.
__launch_bounds__(256)
__global__ void k_agg_pool(const unsigned char* __restrict__ Hs8,
                           const int* __restrict__ offs, const int* __restrict__ cnt,
                           const float* __restrict__ dis, const int* __restrict__ esrc,
                           const float* __restrict__ bias,
                           const int* __restrict__ batch, float* __restrict__ pooled, int N) {
    __shared__ float accL[2][128];
    int tid = threadIdx.x;
    int w = tid >> 6, lane = tid & 63;
    int node0b = blockIdx.x * 32;
    int node0 = node0b + w * 8;
    float b0 = bias[lane * 2], b1 = bias[lane * 2 + 1];
    int gbase = node0b < N ? node0b : N - 1;
    int g_lo = batch[gbase];
    accL[tid >> 7][tid & 127] = 0.f;
    __syncthreads();

    float sA0 = 0.f, sA1 = 0.f, sB0 = 0.f, sB1 = 0.f;

    for (int nn = 0; nn < 8; nn++) {
        int node = node0 + nn;
        if (node < N) {
            int start = offs[node];
            int len = cnt[node];
            float di = dis[node];
            f32x2 h = fp8x2_to_f32_us(*(const unsigned short*)(Hs8 + (size_t)node * D + lane * 2));
            float acc0 = h[0];
            float acc1 = h[1];

            for (int k0 = 0; k0 < len; k0 += 64) {
                int mm = len - k0; if (mm > 64) mm = 64;
                int ep = esrc[start + k0 + (lane < mm ? lane : 0)];
                int j = 0;
                for (; j + 16 <= mm; j += 16) {
                    int s[16]; unsigned short hv[16];
#pragma unroll
                    for (int u = 0; u < 16; u++) s[u] = __shfl(ep, j + u);
#pragma unroll
                    for (int u = 0; u < 16; u++) hv[u] = *(const unsigned short*)(Hs8 + (size_t)s[u] * D + lane * 2);
#pragma unroll
                    for (int u = 0; u < 16; u++) { f32x2 f = fp8x2_to_f32_us(hv[u]); acc0 += f[0]; acc1 += f[1]; }
                }
                for (; j + 4 <= mm; j += 4) {
                    int s[4]; unsigned short hv[4];
#pragma unroll
                    for (int u = 0; u < 4; u++) s[u] = __shfl(ep, j + u);
#pragma unroll
                    for (int u = 0; u < 4; u++) hv[u] = *(const unsigned short*)(Hs8 + (size_t)s[u] * D + lane * 2);
#pragma unroll
                    for (int u = 0; u < 4; u++) { f32x2 f = fp8x2_to_f32_us(hv[u]); acc0 += f[0]; acc1 += f[1]; }
                }
                for (; j < mm; j++) {
                    int s = __shfl(ep, j);
                    f32x2 f = fp8x2_to_f32_us(*(const unsigned short*)(Hs8 + (size_t)s * D + lane * 2));
                    acc0 += f[0]; acc1 += f[1];
                }
            }

            acc0 = acc0 * di + b0;
            acc1 = acc1 * di + b1;
            acc0 = acc0 >= 0.f ? acc0 : 0.01f * acc0;
            acc1 = acc1 >= 0.f ? acc1 : 0.01f * acc1;

            int sel = batch[node] - g_lo;
            if (sel == 0)      { sA0 += acc0; sA1 += acc1; }
            else if (sel == 1) { sB0 += acc0; sB1 += acc1; }
            else {   // block spans >2 graphs: statistically impossible here, kept for correctness
                atomicAdd(&pooled[(g_lo + sel) * D + lane * 2],     acc0);
                atomicAdd(&pooled[(g_lo + sel) * D + lane * 2 + 1], acc1);
            }
        }
    }

    atomicAdd(&accL[0][lane * 2],     sA0);
    atomicAdd(&accL[0][lane * 2 + 1], sA1);
    atomicAdd(&accL[1][lane * 2],     sB0);
    atomicAdd(&accL[1][lane * 2 + 1], sB1);
    __syncthreads();

    if (tid < 128) {
        atomicAdd(&pooled[g_lo * D + tid], accL[0][tid]);
    } else {
        float v = accL[1][tid - 128];
        if (v != 0.f && g_lo + 1 < NUM_GRAPHS)
            atomicAdd(&pooled[(g_lo + 1) * D + (tid - 128)], v);
    }
}

// ---------------- tiny final FC (computes gstart itself) ----------------
__launch_bounds__(128)
__global__ void k_fc(const float* __restrict__ pooled, const int* __restrict__ batch, int N,
                     const float* __restrict__ fcW, const float* __restrict__ fcb,
                     float* __restrict__ out) {
    __shared__ int gs[NUM_GRAPHS + 1];
    int t = threadIdx.x;
    if (t <= NUM_GRAPHS) {
        int g = t;
        int lo = 0, hi = N;
        while (lo < hi) { int mid = (lo + hi) >> 1; if (batch[mid] < g) lo = mid + 1; else hi = mid; }
        gs[t] = lo;   // gs[64] == N
    }
    __syncthreads();
    if (t < NUM_GRAPHS) {
        float s = 0.f;
#pragma unroll 8
        for (int k = 0; k < D; k += 4) {
            f32x4 pv = *(const f32x4*)(pooled + t * D + k);
            f32x4 wv = *(const f32x4*)(fcW + k);
            s += pv[0] * wv[0] + pv[1] * wv[1] + pv[2] * wv[2] + pv[3] * wv[3];
        }
        float c = (float)(gs[t + 1] - gs[t]);
        out[t] = s / fmaxf(c, 1.0f) + fcb[0];
    }
}

extern "C" void kernel_launch(void* const* d_in, const int* in_sizes, int n_in,
                              void* d_out, int out_size, void* d_ws, size_t ws_size,
                              hipStream_t stream) {
    const float* x    = (const float*)d_in[0];
    const int*   ei   = (const int*)d_in[1];
    const int*   batch= (const int*)d_in[2];
    const float* W1   = (const float*)d_in[3];
    const float* b1   = (const float*)d_in[4];
    const float* W2   = (const float*)d_in[5];
    const float* b2   = (const float*)d_in[6];
    const float* fcW  = (const float*)d_in[7];
    const float* fcb  = (const float*)d_in[8];
    float* out = (float*)d_out;

    int N = in_sizes[0] / D;
    int E = in_sizes[1] / 2;

    int NBUCK  = (N + BUCK_N - 1) >> BUCK_SH;  // 391 for N=100000 (<=512)
    int NCHUNK = (E + CHUNK - 1) / CHUNK;      // 196 for E=1.6M

    char* p = (char*)d_ws;
    auto alloc = [&](size_t bytes) { char* r = p; p += (bytes + 255) & ~(size_t)255; return r; };
    int*    cnt    = (int*)   alloc((size_t)N * 4);
    int*    offs   = (int*)   alloc((size_t)N * 4);
    float*  dis    = (float*) alloc((size_t)N * 4);
    int*    gcur   = (int*)   alloc(512 * 4);
    int*    bbuf   = (int*)   alloc((size_t)NBUCK * BCAP * 4);
    int*    esrc   = (int*)   alloc((size_t)NBUCK * BCAP * 4);
    unsigned char* bufA8 = (unsigned char*)alloc((size_t)(NBUCK * BUCK_N) * D); // z1 fp8
    unsigned char* bufC8 = (unsigned char*)alloc((size_t)N * D);   // z2 fp8
    __bf16* Wf2    = (__bf16*)alloc((size_t)D * D * 2);
    float*  pooled = (float*) alloc((size_t)NUM_GRAPHS * D * 4);

    int gblocks = (N + 63) / 64;
    int ablocks = (N + 31) / 32;     // agg kernels: 4 waves/block x 8 nodes/wave

    // zero gcur + pooled (graph-capture-safe async memsets; replaces k_prepW)
    hipMemsetAsync(gcur, 0, 512 * 4, stream);
    hipMemsetAsync(pooled, 0, (size_t)NUM_GRAPHS * D * 4, stream);

    // FUSED: CSR bin (196 blocks) + layer-1 GEMM (1563 blocks, self-packs W1->LDS)
    k_bin_gemm<<<NCHUNK + gblocks, 256, 0, stream>>>(ei, gcur, bbuf, NBUCK, E, NCHUNK,
                                                     x, W1, bufA8, N);
    // CSR place + in-place dis-scaling of z1 rows + Wf2 fragment pack
    k_place<<<NBUCK, 256, 0, stream>>>(bbuf, gcur, esrc, cnt, offs, dis, bufA8, W2, Wf2, N);

    // FUSED layer-1 agg + GEMM2: bufC8 = fp8(dis .* (leaky(agg(bufA8)+b1) @ W2))
    k_agg_gemm<<<ablocks, 256, 0, stream>>>(bufA8, offs, cnt, dis, esrc, b1, Wf2, bufC8, N);

    // layer-2 agg + fused mean-pool (block-level LDS reduce, fence-free)
    k_agg_pool<<<ablocks, 256, 0, stream>>>(bufC8, offs, cnt, dis, esrc, b2,
                                            batch, pooled, N);

    // tiny final FC (separate dispatch guarantees pooled atomics are visible)
    k_fc<<<1, 128, 0, stream>>>(pooled, batch, N, fcW, fcb, out);
}

// Round 12
// 292.700 us; speedup vs baseline: 1.0509x; 1.0509x over previous
//
#include <hip/hip_runtime.h>
#include <hip/hip_bf16.h>
#include <math.h>

#define D 128
#define NUM_GRAPHS 64
#define CHUNK 8192          // edges per binning block
#define BUCK_SH 8           // bucket = col >> 8  (256 nodes per bucket)
#define BUCK_N 256
#define BCAP 8192           // fixed slot capacity per bucket (mean 4096, +64 sigma)
#define PSLICE 8            // pooling blocks per graph
#define HROW 136            // LDS row stride (17x16B) for h1 tile

typedef __bf16 bf16x8 __attribute__((ext_vector_type(8)));
typedef __bf16 bf16x2 __attribute__((ext_vector_type(2)));
typedef float f32x4 __attribute__((ext_vector_type(4)));
typedef float f32x2 __attribute__((ext_vector_type(2)));

// fp8 e4m3 (OCP) helpers — HW converts on gfx950
__device__ inline unsigned char f32_to_fp8(float x) {
    int pk = __builtin_amdgcn_cvt_pk_fp8_f32(x, x, 0, false);
    return (unsigned char)(pk & 0xff);
}
// word-select operand must be a compile-time constant (round-6 lesson)
template <bool HI>
__device__ inline f32x2 fp8x2_to_f32(unsigned int us) {
    return __builtin_amdgcn_cvt_pk_f32_fp8(us, HI);
}
__device__ inline f32x2 fp8x2_to_f32_us(unsigned short us) {
    return __builtin_amdgcn_cvt_pk_f32_fp8((unsigned int)us, false);
}

// W fragment index: idx(k,f) for the 16x16x32 MFMA B-operand layout
__device__ inline int wfrag_idx(int k, int f) {
    int kc = k >> 5, quad = (k >> 3) & 3, j = k & 7;
    int ft = f >> 4, m = f & 15;
    int lane = quad * 16 + m;
    return (((ft << 2) | kc) * 64 + lane) * 8 + j;
}

// ---------------- FUSED: CSR bin pass (blocks [0,nchunk)) + layer-1 GEMM (rest) ----------------
// gemm blocks self-pack W1 -> LDS fragments (no prep dispatch); bin needs only
// memset(gcur). Both halves fully independent -> one launch.
__launch_bounds__(256)
__global__ void k_bin_gemm(const int* __restrict__ ei, int* __restrict__ gcur,
                           int* __restrict__ bbuf, int nbuck, int E, int nchunk,
                           const float* __restrict__ X, const float* __restrict__ W1,
                           unsigned char* __restrict__ Y8, int N) {
    __shared__ int h[512];
    __shared__ int base[512];
    __shared__ __bf16 Wlds[16384];
    int tid = threadIdx.x;

    if (blockIdx.x >= nchunk) {
        // ---- pack W1 (f32, row-major k*D+f) into LDS fragments: coalesced float4 ----
        const float4* w4 = (const float4*)W1;
        for (int i = tid; i < 4096; i += 256) {
            float4 v = w4[i];
            int bkf = i * 4;
            int k = bkf >> 7, f0 = bkf & 127;
            Wlds[wfrag_idx(k, f0 + 0)] = (__bf16)v.x;
            Wlds[wfrag_idx(k, f0 + 1)] = (__bf16)v.y;
            Wlds[wfrag_idx(k, f0 + 2)] = (__bf16)v.z;
            Wlds[wfrag_idx(k, f0 + 3)] = (__bf16)v.w;
        }
        __syncthreads();

        // ---- MFMA gemm: Y8 = fp8(X @ W1), unscaled ----
        int bid = blockIdx.x - nchunk;
        int w = tid >> 6, lane = tid & 63;
        int quad = lane >> 4, m = lane & 15;
        int nodeA = bid * 64 + w * 16 + m;
        if (nodeA >= N) nodeA = N - 1;

        bf16x8 a[4];
#pragma unroll
        for (int kc = 0; kc < 4; kc++) {
            int kb = kc * 32 + quad * 8;
            f32x4 x0 = *(const f32x4*)(X + (size_t)nodeA * D + kb);
            f32x4 x1 = *(const f32x4*)(X + (size_t)nodeA * D + kb + 4);
#pragma unroll
            for (int j = 0; j < 4; j++) { a[kc][j] = (__bf16)x0[j]; a[kc][4 + j] = (__bf16)x1[j]; }
        }

        f32x4 d[8];
#pragma unroll
        for (int ft = 0; ft < 8; ft++) {
            d[ft] = (f32x4){0.f, 0.f, 0.f, 0.f};
#pragma unroll
            for (int kc = 0; kc < 4; kc++) {
                bf16x8 b = *(const bf16x8*)(Wlds + (((ft << 2) | kc) * 64 + lane) * 8);
                d[ft] = __builtin_amdgcn_mfma_f32_16x16x32_bf16(a[kc], b, d[ft], 0, 0, 0);
            }
        }

#pragma unroll
        for (int r = 0; r < 4; r++) {
            int node = bid * 64 + w * 16 + quad * 4 + r;
            if (node < N) {
#pragma unroll
                for (int ft = 0; ft < 8; ft++)
                    Y8[(size_t)node * D + ft * 16 + m] = f32_to_fp8(d[ft][r]);
            }
        }
        return;
    }

    // ---- bin pass ----
    for (int b = tid; b < nbuck; b += 256) h[b] = 0;
    __syncthreads();
    int lo = blockIdx.x * CHUNK;
    if (lo + CHUNK <= E) {
        const int4* c4 = (const int4*)(ei + E + lo);
#pragma unroll 2
        for (int i = tid; i < CHUNK / 4; i += 256) {
            int4 c = c4[i];
            atomicAdd(&h[c.x >> BUCK_SH], 1);
            atomicAdd(&h[c.y >> BUCK_SH], 1);
            atomicAdd(&h[c.z >> BUCK_SH], 1);
            atomicAdd(&h[c.w >> BUCK_SH], 1);
        }
    } else {
        for (int i = tid; i < CHUNK; i += 256) {
            int e = lo + i;
            if (e < E) atomicAdd(&h[ei[E + e] >> BUCK_SH], 1);
        }
    }
    __syncthreads();
    for (int b = tid; b < nbuck; b += 256) {
        base[b] = atomicAdd(&gcur[b], h[b]);
        h[b] = 0;
    }
    __syncthreads();
    if (lo + CHUNK <= E) {
        const int4* r4 = (const int4*)(ei + lo);
        const int4* c4 = (const int4*)(ei + E + lo);
#pragma unroll 2
        for (int i = tid; i < CHUNK / 4; i += 256) {
            int4 r = r4[i];
            int4 c = c4[i];
            int rr[4] = {r.x, r.y, r.z, r.w};
            int cc[4] = {c.x, c.y, c.z, c.w};
#pragma unroll
            for (int u = 0; u < 4; u++) {
                int b = cc[u] >> BUCK_SH;
                int pos = base[b] + atomicAdd(&h[b], 1);
                if (pos < BCAP) bbuf[(size_t)b * BCAP + pos] = rr[u] | ((cc[u] & (BUCK_N - 1)) << 17);
            }
        }
    } else {
        for (int i = tid; i < CHUNK; i += 256) {
            int e = lo + i;
            if (e < E) {
                int r = ei[e], c = ei[E + e];
                int b = c >> BUCK_SH;
                int pos = base[b] + atomicAdd(&h[b], 1);
                if (pos < BCAP) bbuf[(size_t)b * BCAP + pos] = r | ((c & (BUCK_N - 1)) << 17);
            }
        }
    }
}

// ---------------- CSR pass 2 + in-place z1 scaling + Wf2 pack (spread over blocks) ----------------
__global__ void k_place(const int* __restrict__ bbuf, const int* __restrict__ gcur,
                        int* __restrict__ esrc,
                        int* __restrict__ cnt, int* __restrict__ offs,
                        float* __restrict__ dis, unsigned char* __restrict__ z1,
                        const float* __restrict__ W2, __bf16* __restrict__ Wf2, int N) {
    __shared__ int h[256];
    __shared__ int sc[256];
    __shared__ int cur[256];
    __shared__ float sdis[256];
    int b = blockIdx.x, tid = threadIdx.x;

    // Wf2 pack: 42 fragment elems per block (391 blocks cover 16384)
    for (int q = tid; q < 42; q += 256) {
        int idx = b * 42 + q;
        if (idx < 16384) {
            int j = idx & 7, lane = (idx >> 3) & 63, kc = (idx >> 9) & 3, ft = idx >> 11;
            int k = kc * 32 + (lane >> 4) * 8 + j;
            int f = ft * 16 + (lane & 15);
            Wf2[idx] = (__bf16)W2[k * D + f];
        }
    }

    int start = b * BCAP;
    int count = gcur[b]; if (count > BCAP) count = BCAP;
    int end = start + count;
    h[tid] = 0;
    __syncthreads();
    for (int i = start + tid; i < end; i += 256) atomicAdd(&h[(bbuf[i] >> 17) & 255], 1);
    __syncthreads();
    int local = h[tid];
    sc[tid] = local;
    __syncthreads();
    for (int off = 1; off < 256; off <<= 1) {
        int xv = (tid >= off) ? sc[tid - off] : 0;
        __syncthreads();
        sc[tid] += xv;
        __syncthreads();
    }
    int excl = sc[tid] - local;
    cur[tid] = start + excl;
    int c = b * 256 + tid;
    float dv = rsqrtf(1.0f + (float)local);
    sdis[tid] = dv;
    if (c < N) {
        cnt[c]  = local;
        offs[c] = start + excl;
        dis[c]  = dv;                        // deg includes self-loop
    }
    __syncthreads();
    for (int i = start + tid; i < end; i += 256) {
        int p = bbuf[i];
        int pos = atomicAdd(&cur[(p >> 17) & 255], 1);
        esrc[pos] = p & 0x1FFFF;
    }
    // in-place scale of this bucket's z1 rows (r8-proven: agg_gemm 85->61)
    int nrows = N - b * 256; if (nrows > 256) nrows = 256; if (nrows < 0) nrows = 0;
    unsigned int* zp = (unsigned int*)(z1 + (size_t)b * 256 * D);
    for (int i = tid; i < nrows * 32; i += 256) {      // 32 dwords per 128B row
        int row = i >> 5;
        float s = sdis[row];
        unsigned int v = zp[i];
        f32x2 lo = fp8x2_to_f32<false>(v);
        f32x2 hi = fp8x2_to_f32<true>(v);
        unsigned int u = (unsigned int)__builtin_amdgcn_cvt_pk_fp8_f32(lo[0] * s, lo[1] * s, 0, false);
        u = (unsigned int)__builtin_amdgcn_cvt_pk_fp8_f32(hi[0] * s, hi[1] * s, (int)u, true);
        zp[i] = u;
    }
}

// ---------------- FUSED layer-1 agg + GEMM2: z2 = fp8(dis .* (leaky(agg(z1)+b1) @ W2)) ----------------
__launch_bounds__(256)
__global__ void k_agg_gemm(const unsigned char* __restrict__ Hs8,      // z1 scaled fp8
                           const int* __restrict__ offs, const int* __restrict__ cnt,
                           const float* __restrict__ dis, const int* __restrict__ esrc,
                           const float* __restrict__ bias,             // b1
                           const __bf16* __restrict__ Wfrag,           // Wf2
                           unsigned char* __restrict__ Y8, int N) {    // z2 scaled fp8
    __shared__ __bf16 hl[32 * HROW];   // 32 nodes x 128 feats, padded rows (17x16B)
    int tid = threadIdx.x;
    int w = tid >> 6, lane = tid & 63;
    int node0 = blockIdx.x * 32 + w * 8;
    float b0 = bias[lane * 2], b1v = bias[lane * 2 + 1];

    for (int nn = 0; nn < 8; nn++) {
        int node = node0 + nn;
        if (node < N) {
            int start = offs[node];
            int len = cnt[node];
            float di = dis[node];
            f32x2 h = fp8x2_to_f32_us(*(const unsigned short*)(Hs8 + (size_t)node * D + lane * 2));
            float acc0 = h[0];               // self-loop term (already dis-scaled)
            float acc1 = h[1];

            for (int k0 = 0; k0 < len; k0 += 64) {
                int mm = len - k0; if (mm > 64) mm = 64;
                int ep = esrc[start + k0 + (lane < mm ? lane : 0)];
                int j = 0;
                for (; j + 16 <= mm; j += 16) {
                    int s[16]; unsigned short hv[16];
#pragma unroll
                    for (int u = 0; u < 16; u++) s[u] = __shfl(ep, j + u);
#pragma unroll
                    for (int u = 0; u < 16; u++) hv[u] = *(const unsigned short*)(Hs8 + (size_t)s[u] * D + lane * 2);
#pragma unroll
                    for (int u = 0; u < 16; u++) { f32x2 f = fp8x2_to_f32_us(hv[u]); acc0 += f[0]; acc1 += f[1]; }
                }
                for (; j + 4 <= mm; j += 4) {
                    int s[4]; unsigned short hv[4];
#pragma unroll
                    for (int u = 0; u < 4; u++) s[u] = __shfl(ep, j + u);
#pragma unroll
                    for (int u = 0; u < 4; u++) hv[u] = *(const unsigned short*)(Hs8 + (size_t)s[u] * D + lane * 2);
#pragma unroll
                    for (int u = 0; u < 4; u++) { f32x2 f = fp8x2_to_f32_us(hv[u]); acc0 += f[0]; acc1 += f[1]; }
                }
                for (; j < mm; j++) {
                    int s = __shfl(ep, j);
                    f32x2 f = fp8x2_to_f32_us(*(const unsigned short*)(Hs8 + (size_t)s * D + lane * 2));
                    acc0 += f[0]; acc1 += f[1];
                }
            }

            acc0 = acc0 * di + b0;
            acc1 = acc1 * di + b1v;
            acc0 = acc0 >= 0.f ? acc0 : 0.01f * acc0;
            acc1 = acc1 >= 0.f ? acc1 : 0.01f * acc1;
            bf16x2 o; o[0] = (__bf16)acc0; o[1] = (__bf16)acc1;
            *(bf16x2*)&hl[(w * 8 + nn) * HROW + lane * 2] = o;   // h1 -> LDS only
        } else {
            bf16x2 z; z[0] = (__bf16)0.f; z[1] = (__bf16)0.f;
            *(bf16x2*)&hl[(w * 8 + nn) * HROW + lane * 2] = z;
        }
    }
    __syncthreads();

    // ---- MFMA phase: wave w -> row tile (w&1)*16, ft half (w>>1)*4 ----
    int quad = lane >> 4, m = lane & 15;
    int rtile = w & 1, fthalf = w >> 1;
    int lrow = rtile * 16 + m;
    bf16x8 a[4];
#pragma unroll
    for (int kc = 0; kc < 4; kc++)
        a[kc] = *(const bf16x8*)&hl[lrow * HROW + kc * 32 + quad * 8];

    int nb = blockIdx.x * 32 + rtile * 16 + quad * 4;
    float scv[4];
#pragma unroll
    for (int r = 0; r < 4; r++) scv[r] = (nb + r < N) ? dis[nb + r] : 0.f;

#pragma unroll
    for (int ft = 0; ft < 4; ft++) {
        int gft = fthalf * 4 + ft;
        f32x4 dacc = (f32x4){0.f, 0.f, 0.f, 0.f};
#pragma unroll
        for (int kc = 0; kc < 4; kc++) {
            bf16x8 b = *(const bf16x8*)(Wfrag + (((gft << 2) | kc) * 64 + lane) * 8);
            dacc = __builtin_amdgcn_mfma_f32_16x16x32_bf16(a[kc], b, dacc, 0, 0, 0);
        }
#pragma unroll
        for (int r = 0; r < 4; r++) {
            int node = nb + r;
            if (node < N)
                Y8[(size_t)node * D + gft * 16 + m] = f32_to_fp8(dacc[r] * scv[r]);
        }
    }
}

// ---------------- layer-2 CSR aggregation + bias + leaky ReLU (r9-proven lean loop) ----------------
__launch_bounds__(256)
__global__ void k_agg(const unsigned char* __restrict__ Hs8, __bf16* __restrict__ O,
                      const int* __restrict__ offs, const int* __restrict__ cnt,
                      const float* __restrict__ dis, const int* __restrict__ esrc,
                      const float* __restrict__ bias, int N) {
    int wave = (blockIdx.x * 256 + threadIdx.x) >> 6;
    int lane = threadIdx.x & 63;
    int node0 = wave * 8;
    float b0 = bias[lane * 2], b1 = bias[lane * 2 + 1];

    for (int nn = 0; nn < 8; nn++) {
        int node = node0 + nn;
        if (node >= N) return;
        int start = offs[node];
        int len = cnt[node];
        float di = dis[node];
        f32x2 h = fp8x2_to_f32_us(*(const unsigned short*)(Hs8 + (size_t)node * D + lane * 2));
        float acc0 = h[0];               // self-loop term (already dis-scaled)
        float acc1 = h[1];

        for (int k0 = 0; k0 < len; k0 += 64) {
            int mm = len - k0; if (mm > 64) mm = 64;
            int ep = esrc[start + k0 + (lane < mm ? lane : 0)];
            int j = 0;
            for (; j + 16 <= mm; j += 16) {
                int s[16]; unsigned short hv[16];
#pragma unroll
                for (int u = 0; u < 16; u++) s[u] = __shfl(ep, j + u);
#pragma unroll
                for (int u = 0; u < 16; u++) hv[u] = *(const unsigned short*)(Hs8 + (size_t)s[u] * D + lane * 2);
#pragma unroll
                for (int u = 0; u < 16; u++) { f32x2 f = fp8x2_to_f32_us(hv[u]); acc0 += f[0]; acc1 += f[1]; }
            }
            for (; j + 4 <= mm; j += 4) {
                int s[4]; unsigned short hv[4];
#pragma unroll
                for (int u = 0; u < 4; u++) s[u] = __shfl(ep, j + u);
#pragma unroll
                for (int u = 0; u < 4; u++) hv[u] = *(const unsigned short*)(Hs8 + (size_t)s[u] * D + lane * 2);
#pragma unroll
                for (int u = 0; u < 4; u++) { f32x2 f = fp8x2_to_f32_us(hv[u]); acc0 += f[0]; acc1 += f[1]; }
            }
            for (; j < mm; j++) {
                int s = __shfl(ep, j);
                f32x2 f = fp8x2_to_f32_us(*(const unsigned short*)(Hs8 + (size_t)s * D + lane * 2));
                acc0 += f[0]; acc1 += f[1];
            }
        }

        acc0 = acc0 * di + b0;
        acc1 = acc1 * di + b1;
        acc0 = acc0 >= 0.f ? acc0 : 0.01f * acc0;
        acc1 = acc1 >= 0.f ? acc1 : 0.01f * acc1;
        bf16x2 o; o[0] = (__bf16)acc0; o[1] = (__bf16)acc1;
        *(bf16x2*)(O + (size_t)node * D + lane * 2) = o;
    }
}

// ---------------- pooling: per-graph-slice reduction; slice bounds via in-kernel bsearch ----------------
__launch_bounds__(256)
__global__ void k_pool(const __bf16* __restrict__ H, const int* __restrict__ batch, int N,
                       float* __restrict__ pooled) {
    __shared__ float sdata[256 * 9];
    __shared__ int bounds[2];
    int g = blockIdx.x / PSLICE;
    int slice = blockIdx.x - g * PSLICE;
    int t = threadIdx.x;
    if (t < 2) {   // binary search for gstart[g + t]
        int tg = g + t;
        int lo = 0, hi = N;
        while (lo < hi) { int mid = (lo + hi) >> 1; if (batch[mid] < tg) lo = mid + 1; else hi = mid; }
        bounds[t] = lo;
    }
    __syncthreads();
    int gs = bounds[0], ge = bounds[1];
    int cg = ge - gs;
    int r0 = gs + (int)((long long)cg * slice / PSLICE);
    int r1 = gs + (int)((long long)cg * (slice + 1) / PSLICE);
    int rg = t >> 4, fb = t & 15;

    float acc[8];
#pragma unroll
    for (int j = 0; j < 8; j++) acc[j] = 0.f;
    for (int r = r0 + rg; r < r1; r += 16) {
        bf16x8 v = *(const bf16x8*)(H + (size_t)r * D + fb * 8);
#pragma unroll
        for (int j = 0; j < 8; j++) acc[j] += (float)v[j];
    }
#pragma unroll
    for (int j = 0; j < 8; j++) sdata[t * 9 + j] = acc[j];
    __syncthreads();
#pragma unroll
    for (int s = 128; s >= 16; s >>= 1) {
        if (t < s) {
#pragma unroll
            for (int j = 0; j < 8; j++) sdata[t * 9 + j] += sdata[(t + s) * 9 + j];
        }
        __syncthreads();
    }
    if (t < 16) {
#pragma unroll
        for (int j = 0; j < 8; j++) atomicAdd(&pooled[g * D + t * 8 + j], sdata[t * 9 + j]);
    }
}

// ---------------- tiny final FC (computes gstart itself) ----------------
__launch_bounds__(128)
__global__ void k_fc(const float* __restrict__ pooled, const int* __restrict__ batch, int N,
                     const float* __restrict__ fcW, const float* __restrict__ fcb,
                     float* __restrict__ out) {
    __shared__ int gs[NUM_GRAPHS + 1];
    int t = threadIdx.x;
    if (t <= NUM_GRAPHS) {
        int g = t;
        int lo = 0, hi = N;
        while (lo < hi) { int mid = (lo + hi) >> 1; if (batch[mid] < g) lo = mid + 1; else hi = mid; }
        gs[t] = lo;   // gs[64] == N
    }
    __syncthreads();
    if (t < NUM_GRAPHS) {
        float s = 0.f;
#pragma unroll 8
        for (int k = 0; k < D; k += 4) {
            f32x4 pv = *(const f32x4*)(pooled + t * D + k);
            f32x4 wv = *(const f32x4*)(fcW + k);
            s += pv[0] * wv[0] + pv[1] * wv[1] + pv[2] * wv[2] + pv[3] * wv[3];
        }
        float c = (float)(gs[t + 1] - gs[t]);
        out[t] = s / fmaxf(c, 1.0f) + fcb[0];
    }
}

extern "C" void kernel_launch(void* const* d_in, const int* in_sizes, int n_in,
                              void* d_out, int out_size, void* d_ws, size_t ws_size,
                              hipStream_t stream) {
    const float* x    = (const float*)d_in[0];
    const int*   ei   = (const int*)d_in[1];
    const int*   batch= (const int*)d_in[2];
    const float* W1   = (const float*)d_in[3];
    const float* b1   = (const float*)d_in[4];
    const float* W2   = (const float*)d_in[5];
    const float* b2   = (const float*)d_in[6];
    const float* fcW  = (const float*)d_in[7];
    const float* fcb  = (const float*)d_in[8];
    float* out = (float*)d_out;

    int N = in_sizes[0] / D;
    int E = in_sizes[1] / 2;

    int NBUCK  = (N + BUCK_N - 1) >> BUCK_SH;  // 391 for N=100000 (<=512)
    int NCHUNK = (E + CHUNK - 1) / CHUNK;      // 196 for E=1.6M

    char* p = (char*)d_ws;
    auto alloc = [&](size_t bytes) { char* r = p; p += (bytes + 255) & ~(size_t)255; return r; };
    int*    cnt    = (int*)   alloc((size_t)N * 4);
    int*    offs   = (int*)   alloc((size_t)N * 4);
    float*  dis    = (float*) alloc((size_t)N * 4);
    int*    gcur   = (int*)   alloc(512 * 4);
    int*    bbuf   = (int*)   alloc((size_t)NBUCK * BCAP * 4);
    int*    esrc   = (int*)   alloc((size_t)NBUCK * BCAP * 4);
    unsigned char* bufA8 = (unsigned char*)alloc((size_t)(NBUCK * BUCK_N) * D); // z1 fp8
    unsigned char* bufC8 = (unsigned char*)alloc((size_t)N * D);   // z2 fp8
    __bf16* bufB   = (__bf16*)alloc((size_t)N * D * 2);            // h2 bf16
    __bf16* Wf2    = (__bf16*)alloc((size_t)D * D * 2);
    float*  pooled = (float*) alloc((size_t)NUM_GRAPHS * D * 4);

    int gblocks = (N + 63) / 64;
    int ablocks = (N + 31) / 32;     // agg kernels: 4 waves/block x 8 nodes/wave

    // zero gcur + pooled (graph-capture-safe async memsets)
    hipMemsetAsync(gcur, 0, 512 * 4, stream);
    hipMemsetAsync(pooled, 0, (size_t)NUM_GRAPHS * D * 4, stream);

    // FUSED: CSR bin (196 blocks) + layer-1 GEMM (1563 blocks, self-packs W1->LDS)
    k_bin_gemm<<<NCHUNK + gblocks, 256, 0, stream>>>(ei, gcur, bbuf, NBUCK, E, NCHUNK,
                                                     x, W1, bufA8, N);
    // CSR place + in-place dis-scaling of z1 rows + Wf2 fragment pack
    k_place<<<NBUCK, 256, 0, stream>>>(bbuf, gcur, esrc, cnt, offs, dis, bufA8, W2, Wf2, N);

    // FUSED layer-1 agg + GEMM2: bufC8 = fp8(dis .* (leaky(agg(bufA8)+b1) @ W2))
    k_agg_gemm<<<ablocks, 256, 0, stream>>>(bufA8, offs, cnt, dis, esrc, b1, Wf2, bufC8, N);

    // layer-2 agg (lean, streaming bf16 write — r10 showed pool fusion breaks the gather pipeline)
    k_agg<<<ablocks, 256, 0, stream>>>(bufC8, bufB, offs, cnt, dis, esrc, b2, N);

    // pool (fence-free) + tiny FC (separate dispatch guarantees atomic visibility)
    k_pool<<<NUM_GRAPHS * PSLICE, 256, 0, stream>>>(bufB, batch, N, pooled);
    k_fc<<<1, 128, 0, stream>>>(pooled, batch, N, fcW, fcb, out);
}

// Round 13
// 280.292 us; speedup vs baseline: 1.0974x; 1.0443x over previous
//
#include <hip/hip_runtime.h>
#include <hip/hip_bf16.h>
#include <math.h>

#define D 128
#define NUM_GRAPHS 64
#define CHUNK 8192          // edges per binning block
#define BUCK_SH 8           // bucket = col >> 8  (256 nodes per bucket)
#define BUCK_N 256
#define BCAP 8192           // fixed slot capacity per bucket (mean 4096, +64 sigma)
#define PSLICE 8            // pooling blocks per graph
#define HROW 136            // LDS row stride (17x16B) for h1 tile

typedef __bf16 bf16x8 __attribute__((ext_vector_type(8)));
typedef __bf16 bf16x2 __attribute__((ext_vector_type(2)));
typedef float f32x4 __attribute__((ext_vector_type(4)));
typedef float f32x2 __attribute__((ext_vector_type(2)));

// fp8 e4m3 (OCP) helpers — HW converts on gfx950
__device__ inline unsigned char f32_to_fp8(float x) {
    int pk = __builtin_amdgcn_cvt_pk_fp8_f32(x, x, 0, false);
    return (unsigned char)(pk & 0xff);
}
// word-select operand must be a compile-time constant (round-6 lesson)
template <bool HI>
__device__ inline f32x2 fp8x2_to_f32(unsigned int us) {
    return __builtin_amdgcn_cvt_pk_f32_fp8(us, HI);
}
__device__ inline f32x2 fp8x2_to_f32_us(unsigned short us) {
    return __builtin_amdgcn_cvt_pk_f32_fp8((unsigned int)us, false);
}

// ---------------- W -> bf16 B-fragment pack; zero pooled/gcur; graph bounds ----------------
__global__ void k_prepW(const float* __restrict__ Wa, const float* __restrict__ Wb,
                        __bf16* __restrict__ WfA, __bf16* __restrict__ WfB,
                        float* __restrict__ pooled,
                        int* __restrict__ gcur,
                        const int* __restrict__ batch, int* __restrict__ gstart, int N) {
    int gid = blockIdx.x * 256 + threadIdx.x;   // 0..33023
    if (gid < NUM_GRAPHS * D) pooled[gid] = 0.f;
    if (gid < 512) gcur[gid] = 0;
    if (gid >= 16384 && gid <= 16384 + NUM_GRAPHS) {   // 65 threads do binary search
        int g = gid - 16384;
        int lo = 0, hi = N;
        while (lo < hi) { int mid = (lo + hi) >> 1; if (batch[mid] < g) lo = mid + 1; else hi = mid; }
        gstart[g] = lo;
    }
    if (gid >= 32768) return;
    const float* W = (gid < 16384) ? Wa : Wb;
    __bf16* Wf = (gid < 16384) ? WfA : WfB;
    int idx = gid & 16383;
    int j = idx & 7, lane = (idx >> 3) & 63, kc = (idx >> 9) & 3, ft = idx >> 11;
    int k = kc * 32 + (lane >> 4) * 8 + j;
    int f = ft * 16 + (lane & 15);
    Wf[idx] = (__bf16)W[k * D + f];
}

// ---------------- MFMA GEMM body: Y8[N,128](fp8) = X[N,128] @ W  (UNSCALED) ----------------
template <typename T>
__device__ __forceinline__ void gemm_body(int bid, int tid, const T* __restrict__ X,
                                          const __bf16* __restrict__ Wfrag,
                                          unsigned char* __restrict__ Y8, int N) {
    int w = tid >> 6, lane = tid & 63;
    int quad = lane >> 4, m = lane & 15;
    int nodeA = bid * 64 + w * 16 + m;
    if (nodeA >= N) nodeA = N - 1;

    bf16x8 a[4];
#pragma unroll
    for (int kc = 0; kc < 4; kc++) {
        int kb = kc * 32 + quad * 8;
        if constexpr (sizeof(T) == 4) {
            f32x4 x0 = *(const f32x4*)(X + (size_t)nodeA * D + kb);
            f32x4 x1 = *(const f32x4*)(X + (size_t)nodeA * D + kb + 4);
#pragma unroll
            for (int j = 0; j < 4; j++) { a[kc][j] = (__bf16)x0[j]; a[kc][4 + j] = (__bf16)x1[j]; }
        } else {
            a[kc] = *(const bf16x8*)(X + (size_t)nodeA * D + kb);
        }
    }

    f32x4 d[8];
#pragma unroll
    for (int ft = 0; ft < 8; ft++) {
        d[ft] = (f32x4){0.f, 0.f, 0.f, 0.f};
#pragma unroll
        for (int kc = 0; kc < 4; kc++) {
            bf16x8 b = *(const bf16x8*)(Wfrag + (((ft << 2) | kc) * 64 + lane) * 8);
            d[ft] = __builtin_amdgcn_mfma_f32_16x16x32_bf16(a[kc], b, d[ft], 0, 0, 0);
        }
    }

#pragma unroll
    for (int r = 0; r < 4; r++) {
        int node = bid * 64 + w * 16 + quad * 4 + r;
        if (node < N) {
#pragma unroll
            for (int ft = 0; ft < 8; ft++)
                Y8[(size_t)node * D + ft * 16 + m] = f32_to_fp8(d[ft][r]);
        }
    }
}

// ---------------- FUSED: CSR bin pass (blocks [0,nchunk)) + layer-1 GEMM (rest) ----------------
__launch_bounds__(256)
__global__ void k_bin_gemm(const int* __restrict__ ei, int* __restrict__ gcur,
                           int* __restrict__ bbuf, int nbuck, int E, int nchunk,
                           const float* __restrict__ X, const __bf16* __restrict__ Wfrag,
                           unsigned char* __restrict__ Y8, int N) {
    __shared__ int h[512];
    __shared__ int base[512];

    if (blockIdx.x >= nchunk) {
        gemm_body<float>(blockIdx.x - nchunk, threadIdx.x, X, Wfrag, Y8, N);
        return;
    }

    int tid = threadIdx.x;
    for (int b = tid; b < nbuck; b += 256) h[b] = 0;
    __syncthreads();
    int lo = blockIdx.x * CHUNK;
    if (lo + CHUNK <= E) {
        const int4* c4 = (const int4*)(ei + E + lo);
#pragma unroll 2
        for (int i = tid; i < CHUNK / 4; i += 256) {
            int4 c = c4[i];
            atomicAdd(&h[c.x >> BUCK_SH], 1);
            atomicAdd(&h[c.y >> BUCK_SH], 1);
            atomicAdd(&h[c.z >> BUCK_SH], 1);
            atomicAdd(&h[c.w >> BUCK_SH], 1);
        }
    } else {
        for (int i = tid; i < CHUNK; i += 256) {
            int e = lo + i;
            if (e < E) atomicAdd(&h[ei[E + e] >> BUCK_SH], 1);
        }
    }
    __syncthreads();
    for (int b = tid; b < nbuck; b += 256) {
        base[b] = atomicAdd(&gcur[b], h[b]);
        h[b] = 0;
    }
    __syncthreads();
    if (lo + CHUNK <= E) {
        const int4* r4 = (const int4*)(ei + lo);
        const int4* c4 = (const int4*)(ei + E + lo);
#pragma unroll 2
        for (int i = tid; i < CHUNK / 4; i += 256) {
            int4 r = r4[i];
            int4 c = c4[i];
            int rr[4] = {r.x, r.y, r.z, r.w};
            int cc[4] = {c.x, c.y, c.z, c.w};
#pragma unroll
            for (int u = 0; u < 4; u++) {
                int b = cc[u] >> BUCK_SH;
                int pos = base[b] + atomicAdd(&h[b], 1);
                if (pos < BCAP) bbuf[(size_t)b * BCAP + pos] = rr[u] | ((cc[u] & (BUCK_N - 1)) << 17);
            }
        }
    } else {
        for (int i = tid; i < CHUNK; i += 256) {
            int e = lo + i;
            if (e < E) {
                int r = ei[e], c = ei[E + e];
                int b = c >> BUCK_SH;
                int pos = base[b] + atomicAdd(&h[b], 1);
                if (pos < BCAP) bbuf[(size_t)b * BCAP + pos] = r | ((c & (BUCK_N - 1)) << 17);
            }
        }
    }
}

// ---------------- CSR build pass 2 + IN-PLACE z1 SCALING (r8-proven: agg_gemm 85->61) ----------------
__global__ void k_place(const int* __restrict__ bbuf, const int* __restrict__ gcur,
                        int* __restrict__ esrc,
                        int* __restrict__ cnt, int* __restrict__ offs,
                        float* __restrict__ dis, unsigned char* __restrict__ z1, int N) {
    __shared__ int h[256];
    __shared__ int sc[256];
    __shared__ int cur[256];
    __shared__ float sdis[256];
    int b = blockIdx.x, tid = threadIdx.x;
    int start = b * BCAP;
    int count = gcur[b]; if (count > BCAP) count = BCAP;
    int end = start + count;
    h[tid] = 0;
    __syncthreads();
    for (int i = start + tid; i < end; i += 256) atomicAdd(&h[(bbuf[i] >> 17) & 255], 1);
    __syncthreads();
    int local = h[tid];
    sc[tid] = local;
    __syncthreads();
    for (int off = 1; off < 256; off <<= 1) {
        int xv = (tid >= off) ? sc[tid - off] : 0;
        __syncthreads();
        sc[tid] += xv;
        __syncthreads();
    }
    int excl = sc[tid] - local;
    cur[tid] = start + excl;
    int c = b * 256 + tid;
    float dv = rsqrtf(1.0f + (float)local);
    sdis[tid] = dv;
    if (c < N) {
        cnt[c]  = local;
        offs[c] = start + excl;
        dis[c]  = dv;                        // deg includes self-loop
    }
    __syncthreads();
    for (int i = start + tid; i < end; i += 256) {
        int p = bbuf[i];
        int pos = atomicAdd(&cur[(p >> 17) & 255], 1);
        esrc[pos] = p & 0x1FFFF;
    }
    // ---- in-place scale of this bucket's z1 rows ----
    int nrows = N - b * 256; if (nrows > 256) nrows = 256; if (nrows < 0) nrows = 0;
    unsigned int* zp = (unsigned int*)(z1 + (size_t)b * 256 * D);
    for (int i = tid; i < nrows * 32; i += 256) {      // 32 dwords per 128B row
        int row = i >> 5;
        float s = sdis[row];
        unsigned int v = zp[i];
        f32x2 lo = fp8x2_to_f32<false>(v);
        f32x2 hi = fp8x2_to_f32<true>(v);
        unsigned int u = (unsigned int)__builtin_amdgcn_cvt_pk_fp8_f32(lo[0] * s, lo[1] * s, 0, false);
        u = (unsigned int)__builtin_amdgcn_cvt_pk_fp8_f32(hi[0] * s, hi[1] * s, (int)u, true);
        zp[i] = u;
    }
}

// ---------------- FUSED layer-1 agg + GEMM2: z2 = fp8(dis .* (leaky(agg(z1)+b1) @ W2)) ----------------
__launch_bounds__(256)
__global__ void k_agg_gemm(const unsigned char* __restrict__ Hs8,      // z1 scaled fp8
                           const int* __restrict__ offs, const int* __restrict__ cnt,
                           const float* __restrict__ dis, const int* __restrict__ esrc,
                           const float* __restrict__ bias,             // b1
                           const __bf16* __restrict__ Wfrag,           // Wf2
                           unsigned char* __restrict__ Y8, int N) {    // z2 scaled fp8
    __shared__ __bf16 hl[32 * HROW];   // 32 nodes x 128 feats, padded rows (17x16B)
    int tid = threadIdx.x;
    int w = tid >> 6, lane = tid & 63;
    int node0 = blockIdx.x * 32 + w * 8;
    float b0 = bias[lane * 2], b1v = bias[lane * 2 + 1];

    for (int nn = 0; nn < 8; nn++) {
        int node = node0 + nn;
        if (node < N) {
            int start = offs[node];
            int len = cnt[node];
            float di = dis[node];
            f32x2 h = fp8x2_to_f32_us(*(const unsigned short*)(Hs8 + (size_t)node * D + lane * 2));
            float acc0 = h[0];               // self-loop term (already dis-scaled)
            float acc1 = h[1];

            for (int k0 = 0; k0 < len; k0 += 64) {
                int mm = len - k0; if (mm > 64) mm = 64;
                int ep = esrc[start + k0 + (lane < mm ? lane : 0)];
                int j = 0;
                for (; j + 16 <= mm; j += 16) {
                    int s[16]; unsigned short hv[16];
#pragma unroll
                    for (int u = 0; u < 16; u++) s[u] = __shfl(ep, j + u);
#pragma unroll
                    for (int u = 0; u < 16; u++) hv[u] = *(const unsigned short*)(Hs8 + (size_t)s[u] * D + lane * 2);
#pragma unroll
                    for (int u = 0; u < 16; u++) { f32x2 f = fp8x2_to_f32_us(hv[u]); acc0 += f[0]; acc1 += f[1]; }
                }
                for (; j + 4 <= mm; j += 4) {
                    int s[4]; unsigned short hv[4];
#pragma unroll
                    for (int u = 0; u < 4; u++) s[u] = __shfl(ep, j + u);
#pragma unroll
                    for (int u = 0; u < 4; u++) hv[u] = *(const unsigned short*)(Hs8 + (size_t)s[u] * D + lane * 2);
#pragma unroll
                    for (int u = 0; u < 4; u++) { f32x2 f = fp8x2_to_f32_us(hv[u]); acc0 += f[0]; acc1 += f[1]; }
                }
                for (; j < mm; j++) {
                    int s = __shfl(ep, j);
                    f32x2 f = fp8x2_to_f32_us(*(const unsigned short*)(Hs8 + (size_t)s * D + lane * 2));
                    acc0 += f[0]; acc1 += f[1];
                }
            }

            acc0 = acc0 * di + b0;
            acc1 = acc1 * di + b1v;
            acc0 = acc0 >= 0.f ? acc0 : 0.01f * acc0;
            acc1 = acc1 >= 0.f ? acc1 : 0.01f * acc1;
            bf16x2 o; o[0] = (__bf16)acc0; o[1] = (__bf16)acc1;
            *(bf16x2*)&hl[(w * 8 + nn) * HROW + lane * 2] = o;   // h1 -> LDS only
        } else {
            bf16x2 z; z[0] = (__bf16)0.f; z[1] = (__bf16)0.f;
            *(bf16x2*)&hl[(w * 8 + nn) * HROW + lane * 2] = z;
        }
    }
    __syncthreads();

    // ---- MFMA phase: wave w -> row tile (w&1)*16, ft half (w>>1)*4 ----
    int quad = lane >> 4, m = lane & 15;
    int rtile = w & 1, fthalf = w >> 1;
    int lrow = rtile * 16 + m;
    bf16x8 a[4];
#pragma unroll
    for (int kc = 0; kc < 4; kc++)
        a[kc] = *(const bf16x8*)&hl[lrow * HROW + kc * 32 + quad * 8];

    int nb = blockIdx.x * 32 + rtile * 16 + quad * 4;
    float scv[4];
#pragma unroll
    for (int r = 0; r < 4; r++) scv[r] = (nb + r < N) ? dis[nb + r] : 0.f;

#pragma unroll
    for (int ft = 0; ft < 4; ft++) {
        int gft = fthalf * 4 + ft;
        f32x4 dacc = (f32x4){0.f, 0.f, 0.f, 0.f};
#pragma unroll
        for (int kc = 0; kc < 4; kc++) {
            bf16x8 b = *(const bf16x8*)(Wfrag + (((gft << 2) | kc) * 64 + lane) * 8);
            dacc = __builtin_amdgcn_mfma_f32_16x16x32_bf16(a[kc], b, dacc, 0, 0, 0);
        }
#pragma unroll
        for (int r = 0; r < 4; r++) {
            int node = nb + r;
            if (node < N)
                Y8[(size_t)node * D + gft * 16 + m] = f32_to_fp8(dacc[r] * scv[r]);
        }
    }
}

// ---------------- layer-2 CSR aggregation + bias + leaky ReLU (r0 lean loop) ----------------
__launch_bounds__(256)
__global__ void k_agg(const unsigned char* __restrict__ Hs8, __bf16* __restrict__ O,
                      const int* __restrict__ offs, const int* __restrict__ cnt,
                      const float* __restrict__ dis, const int* __restrict__ esrc,
                      const float* __restrict__ bias, int N) {
    int wave = (blockIdx.x * 256 + threadIdx.x) >> 6;
    int lane = threadIdx.x & 63;
    int node0 = wave * 8;
    float b0 = bias[lane * 2], b1 = bias[lane * 2 + 1];

    for (int nn = 0; nn < 8; nn++) {
        int node = node0 + nn;
        if (node >= N) return;
        int start = offs[node];
        int len = cnt[node];
        float di = dis[node];
        f32x2 h = fp8x2_to_f32_us(*(const unsigned short*)(Hs8 + (size_t)node * D + lane * 2));
        float acc0 = h[0];               // self-loop term (already dis-scaled)
        float acc1 = h[1];

        for (int k0 = 0; k0 < len; k0 += 64) {
            int mm = len - k0; if (mm > 64) mm = 64;
            int ep = esrc[start + k0 + (lane < mm ? lane : 0)];
            int j = 0;
            for (; j + 16 <= mm; j += 16) {
                int s[16]; unsigned short hv[16];
#pragma unroll
                for (int u = 0; u < 16; u++) s[u] = __shfl(ep, j + u);
#pragma unroll
                for (int u = 0; u < 16; u++) hv[u] = *(const unsigned short*)(Hs8 + (size_t)s[u] * D + lane * 2);
#pragma unroll
                for (int u = 0; u < 16; u++) { f32x2 f = fp8x2_to_f32_us(hv[u]); acc0 += f[0]; acc1 += f[1]; }
            }
            for (; j + 4 <= mm; j += 4) {
                int s[4]; unsigned short hv[4];
#pragma unroll
                for (int u = 0; u < 4; u++) s[u] = __shfl(ep, j + u);
#pragma unroll
                for (int u = 0; u < 4; u++) hv[u] = *(const unsigned short*)(Hs8 + (size_t)s[u] * D + lane * 2);
#pragma unroll
                for (int u = 0; u < 4; u++) { f32x2 f = fp8x2_to_f32_us(hv[u]); acc0 += f[0]; acc1 += f[1]; }
            }
            for (; j < mm; j++) {
                int s = __shfl(ep, j);
                f32x2 f = fp8x2_to_f32_us(*(const unsigned short*)(Hs8 + (size_t)s * D + lane * 2));
                acc0 += f[0]; acc1 += f[1];
            }
        }

        acc0 = acc0 * di + b0;
        acc1 = acc1 * di + b1;
        acc0 = acc0 >= 0.f ? acc0 : 0.01f * acc0;
        acc1 = acc1 >= 0.f ? acc1 : 0.01f * acc1;
        bf16x2 o; o[0] = (__bf16)acc0; o[1] = (__bf16)acc1;
        *(bf16x2*)(O + (size_t)node * D + lane * 2) = o;
    }
}

// ---------------- pooling: per-graph-slice vectorized reduction (NO fence — r8 lesson) ----------------
__launch_bounds__(256)
__global__ void k_pool(const __bf16* __restrict__ H, const int* __restrict__ gstart,
                       float* __restrict__ pooled) {
    __shared__ float sdata[256 * 9];
    int g = blockIdx.x / PSLICE;
    int slice = blockIdx.x - g * PSLICE;
    int gs = gstart[g], ge = gstart[g + 1];
    int cg = ge - gs;
    int r0 = gs + (int)((long long)cg * slice / PSLICE);
    int r1 = gs + (int)((long long)cg * (slice + 1) / PSLICE);
    int t = threadIdx.x;
    int rg = t >> 4, fb = t & 15;

    float acc[8];
#pragma unroll
    for (int j = 0; j < 8; j++) acc[j] = 0.f;
    for (int r = r0 + rg; r < r1; r += 16) {
        bf16x8 v = *(const bf16x8*)(H + (size_t)r * D + fb * 8);
#pragma unroll
        for (int j = 0; j < 8; j++) acc[j] += (float)v[j];
    }
#pragma unroll
    for (int j = 0; j < 8; j++) sdata[t * 9 + j] = acc[j];
    __syncthreads();
#pragma unroll
    for (int s = 128; s >= 16; s >>= 1) {
        if (t < s) {
#pragma unroll
            for (int j = 0; j < 8; j++) sdata[t * 9 + j] += sdata[(t + s) * 9 + j];
        }
        __syncthreads();
    }
    if (t < 16) {
#pragma unroll
        for (int j = 0; j < 8; j++) atomicAdd(&pooled[g * D + t * 8 + j], sdata[t * 9 + j]);
    }
}

// ---------------- tiny final FC: out[g] = (pooled[g,:] . fcW)/cnt_g + fcb ----------------
__launch_bounds__(64)
__global__ void k_fc(const float* __restrict__ pooled, const int* __restrict__ gstart,
                     const float* __restrict__ fcW, const float* __restrict__ fcb,
                     float* __restrict__ out) {
    int t = threadIdx.x;   // 64 threads, one graph each
    float s = 0.f;
#pragma unroll 8
    for (int k = 0; k < D; k += 4) {
        f32x4 pv = *(const f32x4*)(pooled + t * D + k);
        f32x4 wv = *(const f32x4*)(fcW + k);
        s += pv[0] * wv[0] + pv[1] * wv[1] + pv[2] * wv[2] + pv[3] * wv[3];
    }
    float c = (float)(gstart[t + 1] - gstart[t]);
    out[t] = s / fmaxf(c, 1.0f) + fcb[0];
}

extern "C" void kernel_launch(void* const* d_in, const int* in_sizes, int n_in,
                              void* d_out, int out_size, void* d_ws, size_t ws_size,
                              hipStream_t stream) {
    const float* x    = (const float*)d_in[0];
    const int*   ei   = (const int*)d_in[1];
    const int*   batch= (const int*)d_in[2];
    const float* W1   = (const float*)d_in[3];
    const float* b1   = (const float*)d_in[4];
    const float* W2   = (const float*)d_in[5];
    const float* b2   = (const float*)d_in[6];
    const float* fcW  = (const float*)d_in[7];
    const float* fcb  = (const float*)d_in[8];
    float* out = (float*)d_out;

    int N = in_sizes[0] / D;
    int E = in_sizes[1] / 2;

    int NBUCK  = (N + BUCK_N - 1) >> BUCK_SH;  // 391 for N=100000 (<=512)
    int NCHUNK = (E + CHUNK - 1) / CHUNK;      // 196 for E=1.6M

    char* p = (char*)d_ws;
    auto alloc = [&](size_t bytes) { char* r = p; p += (bytes + 255) & ~(size_t)255; return r; };
    int*    cnt    = (int*)   alloc((size_t)N * 4);
    int*    offs   = (int*)   alloc((size_t)N * 4);
    float*  dis    = (float*) alloc((size_t)N * 4);
    int*    gcur   = (int*)   alloc(512 * 4);
    int*    bbuf   = (int*)   alloc((size_t)NBUCK * BCAP * 4);
    int*    esrc   = (int*)   alloc((size_t)NBUCK * BCAP * 4);
    unsigned char* bufA8 = (unsigned char*)alloc((size_t)(NBUCK * BUCK_N) * D); // z1 fp8 (scaled in place)
    unsigned char* bufC8 = (unsigned char*)alloc((size_t)N * D);   // z2 fp8 (scaled)
    __bf16* bufB   = (__bf16*)alloc((size_t)N * D * 2);            // h2 bf16
    __bf16* Wf1    = (__bf16*)alloc((size_t)D * D * 2);
    __bf16* Wf2    = (__bf16*)alloc((size_t)D * D * 2);
    float*  pooled = (float*) alloc((size_t)NUM_GRAPHS * D * 4);
    int*    gstart = (int*)   alloc((NUM_GRAPHS + 1) * 4);

    int gblocks = (N + 63) / 64;
    int ablocks = (N + 31) / 32;     // agg kernels: 4 waves/block x 8 nodes/wave

    // prep: zeroes gcur/pooled, packs W, graph boundaries
    k_prepW<<<129, 256, 0, stream>>>(W1, W2, Wf1, Wf2, pooled, gcur, batch, gstart, N);

    // FUSED: CSR bin (196 blocks) runs concurrently with layer-1 GEMM (1563 blocks)
    k_bin_gemm<<<NCHUNK + gblocks, 256, 0, stream>>>(ei, gcur, bbuf, NBUCK, E, NCHUNK,
                                                     x, Wf1, bufA8, N);
    // CSR place + in-place dis-scaling of z1 rows (bucket b owns nodes 256b..)
    k_place<<<NBUCK, 256, 0, stream>>>(bbuf, gcur, esrc, cnt, offs, dis, bufA8, N);

    // FUSED layer-1 agg + GEMM2: bufC8 = fp8(dis .* (leaky(agg(bufA8)+b1) @ W2))
    k_agg_gemm<<<ablocks, 256, 0, stream>>>(bufA8, offs, cnt, dis, esrc, b1, Wf2, bufC8, N);

    // layer-2 agg (lean): bufB = leaky(agg(bufC8)+b2)
    k_agg<<<ablocks, 256, 0, stream>>>(bufC8, bufB, offs, cnt, dis, esrc, b2, N);

    // pool (fence-free) + tiny FC (separate dispatch guarantees atomic visibility)
    k_pool<<<NUM_GRAPHS * PSLICE, 256, 0, stream>>>(bufB, gstart, pooled);
    k_fc<<<1, 64, 0, stream>>>(pooled, gstart, fcW, fcb, out);
}